// Round 11
// baseline (232.860 us; speedup 1.0000x reference)
//
#include <hip/hip_runtime.h>

// out[n,i,j] = sum_k x[n,i,k] * w[i,j,k] + b[i,j]   (N=128, D=512)
// One block per i. 64 half-chunk bodies (16 j-rows x 256 k = 16KB f32 W).
// f32 ring of THREE slots (48KB), wave-private rows (wave w gldses+converts
// rows {2w,2w+1} only) -> glds(h+3) issued 2 bodies before its convert
// deadline; counted vmcnt(8/12) never drains the queue. 2x8KB bf16 bufs
// (one barrier per body). R4's X-staging prologue verbatim.
// LDS = 49152 + 16384 + 2048 = 67584 B (same as R4; 2 blocks/CU).

#define Dd 512
#define DD (512 * 512)

typedef __attribute__((ext_vector_type(8))) short bf16x8;
typedef __attribute__((ext_vector_type(4))) short bf16x4;
typedef __attribute__((ext_vector_type(4))) float f32x4;

__device__ __forceinline__ short f2bf(float f) {
    unsigned u = __builtin_bit_cast(unsigned, f);
    u += 0x7FFFu + ((u >> 16) & 1u);      // RNE
    return (short)(u >> 16);
}

__device__ __forceinline__ void glds16(const float* g, float* l) {
    __builtin_amdgcn_global_load_lds(
        (const __attribute__((address_space(1))) void*)g,
        (__attribute__((address_space(3))) void*)l, 16, 0, 0);
}

__global__ __launch_bounds__(512, 4)
void linear3d_kernel(const float* __restrict__ x,
                     const float* __restrict__ w,
                     const float* __restrict__ b,
                     float* __restrict__ out) {
    const int i    = blockIdx.x;
    const int tid  = threadIdx.x;
    const int lane = tid & 63;
    const int wid  = tid >> 6;            // wave owns n-rows [wid*16,+16) and W-rows {2wid,2wid+1}
    const int row16 = lane & 15;
    const int cg    = lane >> 4;

    __shared__ float f32r[3][4096];       // 48 KB ring: half-chunk slots [16 rows x 256 f32]
    __shared__ short bfb[2][4096];        // 16 KB: bf16 half-chunk bufs [16 rows x 256 bf16]
    __shared__ float ldsb[Dd];            // 2 KB bias

    const float* xi = x + (size_t)i * Dd;         // x[n,i,k] = xi[n*DD + k]
    const float* wi = w + (size_t)i * DD;         // w[i,j,k] = wi[j*Dd + k]

    ldsb[tid] = b[i * Dd + tid];

    // glds half-chunk H into SLOT: wave's 2 rows, 1KB contiguous per row
#define GLDS(H, SLOT) do {                                                     \
    int p_ = (H) >> 1, kh_ = (H) & 1;                                          \
    _Pragma("unroll")                                                          \
    for (int q = 0; q < 2; ++q) {                                              \
        int jr_ = 2 * wid + q;                                                 \
        glds16(wi + (size_t)(p_ * 16 + jr_) * 512 + kh_ * 256 + lane * 4,      \
               &f32r[SLOT][jr_ * 256]);                                        \
    }                                                                          \
} while (0)

    // self-convert wave's 2 rows of SLOT -> bfb[BUF] (swizzled)
#define CONV(SLOT, BUF) do {                                                   \
    _Pragma("unroll")                                                          \
    for (int q = 0; q < 2; ++q) {                                              \
        int jr_ = 2 * wid + q;                                                 \
        float4 v_ = *(const float4*)(&f32r[SLOT][jr_ * 256 + lane * 4]);       \
        bf16x4 h_ = { f2bf(v_.x), f2bf(v_.y), f2bf(v_.z), f2bf(v_.w) };        \
        int byte_ = jr_ * 512 + ((lane * 8) ^ ((jr_ & 7) << 4));               \
        *(bf16x4*)((char*)&bfb[BUF][0] + byte_) = h_;                          \
    }                                                                          \
} while (0)

    GLDS(0, 0); GLDS(1, 1); GLDS(2, 2);

    // ---- X staging: R4 prologue verbatim (scratch = bfb area, 16KB)
    short* xs = &bfb[0][0];
    bf16x8 xf[16];
    for (int r = 0; r < 8; ++r) {
        __syncthreads();
        #pragma unroll
        for (int p = 0; p < 4; ++p) {
            int idx4 = tid + p * 512;     // 16 rows x 128 float4
            int row = idx4 >> 7, c4 = idx4 & 127;
            float4 v = *(const float4*)(xi + (size_t)(r * 16 + row) * DD + c4 * 4);
            bf16x4 h = { f2bf(v.x), f2bf(v.y), f2bf(v.z), f2bf(v.w) };
            int byte = (row * 1024 + c4 * 8) ^ ((row & 7) << 4);
            *(bf16x4*)((char*)xs + byte) = h;
        }
        __syncthreads();
        if (wid == r) {
            #pragma unroll
            for (int s = 0; s < 16; ++s) {
                int byte = (row16 * 1024 + s * 64 + cg * 16) ^ ((row16 & 7) << 4);
                xf[s] = *(const bf16x8*)((const char*)xs + byte);
            }
        }
    }
    __syncthreads();                      // drains glds(0..2) and X loads

    CONV(0, 0);                           // half-chunk 0 -> bfb[0]
    asm volatile("s_waitcnt lgkmcnt(0)" ::: "memory");
    __builtin_amdgcn_s_barrier();
    __builtin_amdgcn_sched_barrier(0);

    f32x4 accA = {0.f, 0.f, 0.f, 0.f}, accB = {0.f, 0.f, 0.f, 0.f};

    // Body(h): [glds(h+3) -> slot h%3 (this wave's own rows, freed by its own
    // convert in body h-1)] [8 MFMA from bfb[h&1]] [odd h: store chunk h>>1]
    // [vmcnt(N); CONV(slot (h+1)%3 -> bfb[(h+1)&1]); lgkm0; s_barrier].
    // Per-wave in-order vmem stream: {2 glds}[odd: 4 st] per body.
    // newer-than-glds(h+1): even h = 8, odd h = 12; tail: b61=10, b62=4.
#define BODY(H, SG, SC, PAR, VMSTR, DO_GLDS, DO_WC) do {                       \
    if (DO_GLDS) GLDS((H) + 3, SG);                                            \
    _Pragma("unroll")                                                          \
    for (int s = 0; s < 8; s += 2) {                                           \
        int byA_ = row16 * 512 + ((s * 64 + cg * 16) ^ ((row16 & 7) << 4));    \
        int byB_ = row16 * 512 + (((s + 1) * 64 + cg * 16) ^ ((row16 & 7) << 4)); \
        bf16x8 wfA_ = *(const bf16x8*)((const char*)&bfb[PAR][0] + byA_);      \
        bf16x8 wfB_ = *(const bf16x8*)((const char*)&bfb[PAR][0] + byB_);      \
        accA = __builtin_amdgcn_mfma_f32_16x16x32_bf16(xf[(PAR)*8 + s], wfA_, accA, 0, 0, 0);     \
        accB = __builtin_amdgcn_mfma_f32_16x16x32_bf16(xf[(PAR)*8 + s + 1], wfB_, accB, 0, 0, 0); \
    }                                                                          \
    if (PAR) {                                                                 \
        int j_ = ((H) >> 1) * 16 + row16;                                      \
        float bias_ = ldsb[j_];                                                \
        _Pragma("unroll")                                                      \
        for (int r_ = 0; r_ < 4; ++r_) {                                       \
            int n_ = wid * 16 + cg * 4 + r_;                                   \
            out[(size_t)n_ * DD + (size_t)i * Dd + j_] =                       \
                accA[r_] + accB[r_] + bias_;                                   \
        }                                                                      \
        accA = (f32x4){0.f, 0.f, 0.f, 0.f};                                    \
        accB = (f32x4){0.f, 0.f, 0.f, 0.f};                                    \
    }                                                                          \
    if (DO_WC) {                                                               \
        asm volatile("s_waitcnt " VMSTR ::: "memory");                         \
        __builtin_amdgcn_sched_barrier(0);                                     \
        CONV(SC, (PAR) ^ 1);                                                   \
        asm volatile("s_waitcnt lgkmcnt(0)" ::: "memory");                     \
        __builtin_amdgcn_s_barrier();                                          \
        __builtin_amdgcn_sched_barrier(0);                                     \
    }                                                                          \
} while (0)

    #pragma unroll 1
    for (int u = 0; u < 10; ++u) {
        int h = 6 * u;
        BODY(h + 0, 0, 1, 0, "vmcnt(8)",  true, true);
        BODY(h + 1, 1, 2, 1, "vmcnt(12)", true, true);
        BODY(h + 2, 2, 0, 0, "vmcnt(8)",  true, true);
        BODY(h + 3, 0, 1, 1, "vmcnt(12)", true, true);
        BODY(h + 4, 1, 2, 0, "vmcnt(8)",  true, true);
        BODY(h + 5, 2, 0, 1, "vmcnt(12)", true, true);
    }
    // tail: h = 60..63 (no glds past 63)
    BODY(60, 0, 1, 0, "vmcnt(8)",  true,  true);   // issues glds(63)
    BODY(61, 1, 2, 1, "vmcnt(10)", false, true);
    BODY(62, 2, 0, 0, "vmcnt(4)",  false, true);   // waits glds(63)
    BODY(63, 0, 1, 1, "vmcnt(0)",  false, false);  // MFMA + final stores only

#undef BODY
#undef CONV
#undef GLDS
}

extern "C" void kernel_launch(void* const* d_in, const int* in_sizes, int n_in,
                              void* d_out, int out_size, void* d_ws, size_t ws_size,
                              hipStream_t stream) {
    const float* x = (const float*)d_in[0];
    const float* w = (const float*)d_in[1];
    const float* b = (const float*)d_in[2];
    float* out = (float*)d_out;
    linear3d_kernel<<<dim3(Dd), dim3(512), 0, stream>>>(x, w, b, out);
}

// Round 12
// 209.282 us; speedup vs baseline: 1.1127x; 1.1127x over previous
//
#include <hip/hip_runtime.h>

// out[n,i,j] = sum_k x[n,i,k] * w[i,j,k] + b[i,j]   (N=128, D=512)
// R4 structure VERBATIM (best: 184.8us across 11 rounds) + two locality-only
// changes: (1) bijective XCD swizzle: 64 consecutive i per XCD -> contiguous
// W panels + adjacent X rows per XCD-L2/DRAM stream; (2) nontemporal out
// stores (write-once data stays out of L2's way).

#define Dd 512
#define DD (512 * 512)
#define CHUNK 16
#define NCHUNK 32

typedef __attribute__((ext_vector_type(8))) short bf16x8;
typedef __attribute__((ext_vector_type(4))) short bf16x4;
typedef __attribute__((ext_vector_type(4))) float f32x4;

__device__ __forceinline__ short f2bf(float f) {
    unsigned u = __builtin_bit_cast(unsigned, f);
    u += 0x7FFFu + ((u >> 16) & 1u);      // RNE
    return (short)(u >> 16);
}

__device__ __forceinline__ void glds16(const float* g, float* l) {
    __builtin_amdgcn_global_load_lds(
        (const __attribute__((address_space(1))) void*)g,
        (__attribute__((address_space(3))) void*)l, 16, 0, 0);
}

__global__ __launch_bounds__(512, 4)
void linear3d_kernel(const float* __restrict__ x,
                     const float* __restrict__ w,
                     const float* __restrict__ b,
                     float* __restrict__ out) {
    // XCD swizzle: blockIdx round-robins XCDs; regroup so XCD g gets the
    // contiguous range i in [g*64, (g+1)*64).  512 % 8 == 0 -> bijective.
    const int i    = (blockIdx.x & 7) * 64 + (blockIdx.x >> 3);
    const int tid  = threadIdx.x;
    const int lane = tid & 63;
    const int wid  = tid >> 6;            // wave owns n-rows [wid*16, +16)
    const int row16 = lane & 15;
    const int cg    = lane >> 4;

    __shared__ float f32s[CHUNK * Dd];    // 32 KB f32 W chunk (glds target)
    __shared__ short b16[2][CHUNK * Dd];  // 2 x 16 KB swizzled bf16 W chunk
    __shared__ float ldsb[Dd];            // bias row

    const float* xi = x + (size_t)i * Dd;         // x[n,i,k] = xi[n*DD + k]
    const float* wi = w + (size_t)i * DD;         // w[i,j,k] = wi[j*Dd + k]

    ldsb[tid] = b[i * Dd + tid];

    // ---- issue W chunk 0 -> f32s (latency hidden under X staging)
    #pragma unroll
    for (int q = 0; q < 4; ++q)
        glds16(wi + (size_t)(wid * 256 + q * 64 + lane) * 4,
               &f32s[(wid * 256 + q * 64) * 4]);

    // ---- stage X -> per-wave bf16 fragments via b16 scratch (R4 verbatim)
    short* xs = &b16[0][0];
    bf16x8 xf[16];
    for (int r = 0; r < 8; ++r) {
        __syncthreads();
        #pragma unroll
        for (int p = 0; p < 4; ++p) {
            int idx4 = tid + p * 512;     // 16 rows x 128 float4
            int row = idx4 >> 7, c4 = idx4 & 127;
            float4 v = *(const float4*)(xi + (size_t)(r * 16 + row) * DD + c4 * 4);
            bf16x4 h = { f2bf(v.x), f2bf(v.y), f2bf(v.z), f2bf(v.w) };
            int byte = (row * 1024 + c4 * 8) ^ ((row & 7) << 4);
            *(bf16x4*)((char*)xs + byte) = h;
        }
        __syncthreads();
        if (wid == r) {
            #pragma unroll
            for (int s = 0; s < 16; ++s) {
                int byte = (row16 * 1024 + s * 64 + cg * 16) ^ ((row16 & 7) << 4);
                xf[s] = *(const bf16x8*)((const char*)xs + byte);
            }
        }
    }
    __syncthreads();   // staging reads done; glds(0) drained & visible

    // ---- convert W0: f32s -> b16[0]
    #pragma unroll
    for (int p = 0; p < 4; ++p) {
        int idx4 = tid + p * 512;
        int row = idx4 >> 7, c4 = idx4 & 127;
        float4 v = *(const float4*)(f32s + idx4 * 4);
        bf16x4 h = { f2bf(v.x), f2bf(v.y), f2bf(v.z), f2bf(v.w) };
        int byte = (row * 1024 + c4 * 8) ^ ((row & 7) << 4);
        *(bf16x4*)((char*)&b16[0][0] + byte) = h;
    }
    asm volatile("s_waitcnt lgkmcnt(0)" ::: "memory");
    __builtin_amdgcn_s_barrier();

    // ---- issue W chunk 1 -> f32s
    #pragma unroll
    for (int q = 0; q < 4; ++q)
        glds16(wi + (size_t)(CHUNK * Dd) + (size_t)(wid * 256 + q * 64 + lane) * 4,
               &f32s[(wid * 256 + q * 64) * 4]);

    const int nb = wid * 16;
    float* outbase = out + (size_t)i * Dd;

    // ---- main loop: R4 verbatim except nontemporal out stores
    for (int c = 0; c < NCHUNK; ++c) {
        const char* buf = (const char*)&b16[c & 1][0];
        f32x4 acc = {0.f, 0.f, 0.f, 0.f};
        #pragma unroll
        for (int s = 0; s < 16; ++s) {
            int byte = (row16 * 1024 + s * 64 + cg * 16) ^ ((row16 & 7) << 4);
            bf16x8 wf = *(const bf16x8*)(buf + byte);
            acc = __builtin_amdgcn_mfma_f32_16x16x32_bf16(xf[s], wf, acc, 0, 0, 0);
        }
        float bias = ldsb[c * 16 + row16];
        #pragma unroll
        for (int r = 0; r < 4; ++r) {
            int n = nb + cg * 4 + r;
            __builtin_nontemporal_store(acc[r] + bias,
                outbase + (size_t)n * DD + c * CHUNK + row16);
        }

        if (c + 1 < NCHUNK) {
            // glds(c+1) retired when only the 4 stores are newer
            asm volatile("s_waitcnt lgkmcnt(0) vmcnt(4)" ::: "memory");
            __builtin_amdgcn_s_barrier();

            char* dstb = (char*)&b16[(c + 1) & 1][0];
            #pragma unroll
            for (int p = 0; p < 4; ++p) {
                int idx4 = tid + p * 512;
                int row = idx4 >> 7, cu = idx4 & 127;
                float4 v = *(const float4*)(f32s + idx4 * 4);
                bf16x4 h = { f2bf(v.x), f2bf(v.y), f2bf(v.z), f2bf(v.w) };
                int byte = (row * 1024 + cu * 8) ^ ((row & 7) << 4);
                *(bf16x4*)(dstb + byte) = h;
            }
            asm volatile("s_waitcnt lgkmcnt(0)" ::: "memory");
            __builtin_amdgcn_s_barrier();

            if (c + 2 < NCHUNK) {
                const float* src = wi + (size_t)(c + 2) * (CHUNK * Dd);
                #pragma unroll
                for (int q = 0; q < 4; ++q)
                    glds16(src + (size_t)(wid * 256 + q * 64 + lane) * 4,
                           &f32s[(wid * 256 + q * 64) * 4]);
            }
        }
    }
}

extern "C" void kernel_launch(void* const* d_in, const int* in_sizes, int n_in,
                              void* d_out, int out_size, void* d_ws, size_t ws_size,
                              hipStream_t stream) {
    const float* x = (const float*)d_in[0];
    const float* w = (const float*)d_in[1];
    const float* b = (const float*)d_in[2];
    float* out = (float*)d_out;
    linear3d_kernel<<<dim3(Dd), dim3(512), 0, stream>>>(x, w, b, out);
}